// Round 2
// 206.120 us; speedup vs baseline: 1.0028x; 1.0028x over previous
//
#include <hip/hip_runtime.h>
#include <hip/hip_bf16.h>
#include <cstdint>

#define BATCH 4096
#define LAT   2048
#define NFREQ 2074
#define KPAD  2112   // NFREQ padded up to a multiple of 64 (zero-filled); 66 K-iters

typedef __bf16 bf16x8 __attribute__((ext_vector_type(8)));
typedef float  f32x4  __attribute__((ext_vector_type(4)));

__device__ __forceinline__ unsigned short f2bf(float f) {
    unsigned int u = __float_as_uint(f);
    u = (u + 0x7fffu + ((u >> 16) & 1u)) >> 16;
    return (unsigned short)u;
}

__device__ __forceinline__ void gload_lds16(const unsigned short* g, unsigned short* l) {
    __builtin_amdgcn_global_load_lds(
        (const __attribute__((address_space(1))) unsigned int*)g,
        (__attribute__((address_space(3))) unsigned int*)l,
        16, 0, 0);
}

// ---------------------------------------------------------------------------
// prep: blocks [0,4096)    -> cast x fp32 -> bf16 (8 elem/thread) + init max
//       blocks [4096,5152) -> transpose+cast W  -> WT  [LAT][KPAD]
//       blocks [5152,6208) -> transpose+cast cb -> cosT[LAT][KPAD]
__global__ void prep_kernel(const float* __restrict__ x,
                            const float* __restrict__ W,
                            const float* __restrict__ cb,
                            unsigned short* __restrict__ xb,
                            unsigned short* __restrict__ WT,
                            unsigned short* __restrict__ cosT,
                            float* __restrict__ maxp) {
    __shared__ float t[64][65];
    const int bid = blockIdx.x;
    const int tid = threadIdx.x;
    if (bid < 4096) {
        int i = bid * 256 + tid;
        const float4* x4 = (const float4*)x;
        float4 a = x4[2 * i];
        float4 b = x4[2 * i + 1];
        union { unsigned short us[8]; uint4 v; } p;
        p.us[0] = f2bf(a.x); p.us[1] = f2bf(a.y); p.us[2] = f2bf(a.z); p.us[3] = f2bf(a.w);
        p.us[4] = f2bf(b.x); p.us[5] = f2bf(b.y); p.us[6] = f2bf(b.z); p.us[7] = f2bf(b.w);
        ((uint4*)xb)[i] = p.v;
        if (i == 0) *maxp = -__builtin_inff();
        return;
    }
    int b2 = bid - 4096;
    const float* in     = (b2 < 1056) ? W  : cb;
    unsigned short* out = (b2 < 1056) ? WT : cosT;
    if (b2 >= 1056) b2 -= 1056;
    const int c0 = (b2 % 32) * 64;
    const int r0 = (b2 / 32) * 64;
    for (int i = tid; i < 4096; i += 256) {
        int rr = i >> 6, cc = i & 63;
        int r = r0 + rr;
        float v = (r < NFREQ) ? in[(size_t)r * LAT + c0 + cc] : 0.0f;
        t[rr][cc] = v;
    }
    __syncthreads();
    for (int i = tid; i < 4096; i += 256) {
        int cc = i >> 6, rr = i & 63;
        out[(size_t)(c0 + cc) * KPAD + (r0 + rr)] = f2bf(t[rr][cc]);
    }
}

// ---------------------------------------------------------------------------
// LDS chunk swizzle: tile rows are 64B (32 bf16); unswizzled fragment reads at
// row*64B + quad*16B hit bank-group 16*(row&1)+4*quad -> each 8-lane batch
// used only 2 of 8 16B groups (round-0: 6.29M conflict cycles in gemm2 = ~20%
// of CU cycles). Store logical chunk c of row r at physical c ^ ((r>>1)&3):
// batches now span all 8 groups. Applied both-sides (rule #21, XOR is its own
// inverse): pre-swizzled global_load_lds SOURCE (LDS dest stays linear) + the
// same XOR on the ds_read address. All row-base terms (wave/mi/ni offsets) are
// multiples of 16 -> contribute 0 to (r>>1)&3, so only srow/l16 enter the XOR.
// Coalescing preserved: the permutation stays inside each row's 64B group.
//
// NOTE (round-1 post-mortem): hipLaunchCooperativeKernel inside the
// graph-captured kernel_launch silently fails -> output all zeros. Grid-wide
// sync is OFF LIMITS here; global max -> scale stays a separate dispatch.

// GEMM1: C[m][n] = sum_k A[m][k]*Bt[n][k], bf16 out.
// 128x64 block tile, 4 waves (2m x 2n of 64x32 wave tiles), BK=32, 3-stage
// circular LDS, one raw s_barrier per iter, vmcnt(3) straddle. Grid 512 =
// 2 blocks/CU.
template <int N, int K>
__global__ __launch_bounds__(256, 2)
void gemm1_kernel(const unsigned short* __restrict__ A,
                  const unsigned short* __restrict__ Bt,
                  unsigned short* __restrict__ C) {
    __shared__ alignas(16) unsigned short As[3][128 * 32];
    __shared__ alignas(16) unsigned short Bs[3][64 * 32];

    const int tid  = threadIdx.x;
    const int wave = tid >> 6;
    const int lane = tid & 63;
    const int wm   = (wave >> 1) * 64;
    const int wn   = (wave & 1) * 32;
    const int quad = lane >> 4;
    const int l16  = lane & 15;

    const int mBase = blockIdx.y * 128;
    const int nBase = blockIdx.x * 64;

    const int srow = lane >> 2;                              // row within 16-row chunk
    const int sk   = (((lane & 3) ^ ((srow >> 1) & 3))) * 8; // swizzled k-offset (elems)

    const unsigned short* Ab1 = A  + (size_t)(mBase + (wave * 2 + 0) * 16 + srow) * K + sk;
    const unsigned short* Ab2 = A  + (size_t)(mBase + (wave * 2 + 1) * 16 + srow) * K + sk;
    const unsigned short* Bb1 = Bt + (size_t)(nBase + wave * 16 + srow) * K + sk;

    const int aoff1 = ((wave * 2 + 0) * 16) * 32;
    const int aoff2 = ((wave * 2 + 1) * 16) * 32;
    const int boff  = (wave * 16) * 32;

    // fragment-read physical chunk: quad ^ ((row>>1)&3); row = <mult of 16> + l16
    const int pc = (quad ^ ((l16 >> 1) & 3)) * 8;

    constexpr int NIT = K / 32;
    gload_lds16(Ab1, &As[0][aoff1]);
    gload_lds16(Ab2, &As[0][aoff2]);
    gload_lds16(Bb1, &Bs[0][boff]);

    f32x4 acc[4][2] = {};
    int bc = 0;
    for (int j = 0; j < NIT; ++j) {
        const int bn = (bc == 2) ? 0 : bc + 1;
        if (j + 1 < NIT) {
            const int k0 = (j + 1) * 32;
            gload_lds16(Ab1 + k0, &As[bn][aoff1]);
            gload_lds16(Ab2 + k0, &As[bn][aoff2]);
            gload_lds16(Bb1 + k0, &Bs[bn][boff]);
            asm volatile("s_waitcnt vmcnt(3)\n\ts_barrier" ::: "memory");
        } else {
            asm volatile("s_waitcnt vmcnt(0)\n\ts_barrier" ::: "memory");
        }
        bf16x8 af[4], bfr[2];
#pragma unroll
        for (int mi = 0; mi < 4; ++mi)
            af[mi] = *(const bf16x8*)&As[bc][(wm + mi * 16 + l16) * 32 + pc];
#pragma unroll
        for (int ni = 0; ni < 2; ++ni)
            bfr[ni] = *(const bf16x8*)&Bs[bc][(wn + ni * 16 + l16) * 32 + pc];
#pragma unroll
        for (int mi = 0; mi < 4; ++mi)
#pragma unroll
            for (int ni = 0; ni < 2; ++ni)
                acc[mi][ni] = __builtin_amdgcn_mfma_f32_16x16x32_bf16(
                    af[mi], bfr[ni], acc[mi][ni], 0, 0, 0);
        bc = bn;
    }

    // C/D layout: col = lane&15, row = quad*4 + reg
#pragma unroll
    for (int mi = 0; mi < 4; ++mi)
#pragma unroll
        for (int ni = 0; ni < 2; ++ni) {
            int col = nBase + wn + ni * 16 + l16;
#pragma unroll
            for (int r = 0; r < 4; ++r) {
                int row = mBase + wm + mi * 16 + quad * 4 + r;
                C[(size_t)row * N + col] = f2bf(acc[mi][ni][r]);
            }
        }
}

// ---------------------------------------------------------------------------
// GEMM2: out[m][n] = sum_k A[m][k]*Bt[n][k], fp32 out + fused global max.
// Round-2 restructure: 128x128 block tile, 256 threads = 4 waves of 64x64
// wave tiles (acc[4][4], m97 shape). LDS:MFMA demand ratio drops 1.7 -> 1.14
// (8 ds_read_b128 per 262 kFLOP instead of 6 per 131 kFLOP) -- round 0 showed
// the 64x32 scheme was LDS-BW-bound at 27% MfmaUtil. 3-stage circular LDS,
// vmcnt(4) straddle (4 DMAs/wave/iter: 2 A-chunks + 2 B-chunks), swizzled.
// Max: wave-reduce -> LDS -> ONE atomic per block (512 total).
template <int N, int K>
__global__ __launch_bounds__(256, 2)
void gemm2_kernel(const unsigned short* __restrict__ A,
                  const unsigned short* __restrict__ Bt,
                  float* __restrict__ C,
                  float* __restrict__ maxp) {
    __shared__ alignas(16) unsigned short As[3][128 * 32];
    __shared__ alignas(16) unsigned short Bs[3][128 * 32];
    __shared__ float redbuf[4];

    const int tid  = threadIdx.x;
    const int wave = tid >> 6;          // 0..3
    const int lane = tid & 63;
    const int wm   = (wave >> 1) * 64;  // m-half
    const int wn   = (wave & 1) * 64;   // n-half
    const int quad = lane >> 4;
    const int l16  = lane & 15;

    const int mBase = blockIdx.y * 128;
    const int nBase = blockIdx.x * 128;

    const int srow = lane >> 2;
    const int sk   = (((lane & 3) ^ ((srow >> 1) & 3))) * 8; // swizzled source

    // wave stages A rows [wave*32, wave*32+32) and B rows likewise (2 chunks each)
    const unsigned short* Ab1 = A  + (size_t)(mBase + (wave * 2 + 0) * 16 + srow) * K + sk;
    const unsigned short* Ab2 = A  + (size_t)(mBase + (wave * 2 + 1) * 16 + srow) * K + sk;
    const unsigned short* Bb1 = Bt + (size_t)(nBase + (wave * 2 + 0) * 16 + srow) * K + sk;
    const unsigned short* Bb2 = Bt + (size_t)(nBase + (wave * 2 + 1) * 16 + srow) * K + sk;

    const int off1 = ((wave * 2 + 0) * 16) * 32;
    const int off2 = ((wave * 2 + 1) * 16) * 32;

    const int pc = (quad ^ ((l16 >> 1) & 3)) * 8;            // swizzled frag read

    constexpr int NIT = K / 32;
    gload_lds16(Ab1, &As[0][off1]);
    gload_lds16(Ab2, &As[0][off2]);
    gload_lds16(Bb1, &Bs[0][off1]);
    gload_lds16(Bb2, &Bs[0][off2]);

    f32x4 acc[4][4] = {};
    int bc = 0;
    for (int j = 0; j < NIT; ++j) {
        const int bn = (bc == 2) ? 0 : bc + 1;
        if (j + 1 < NIT) {
            const int k0 = (j + 1) * 32;
            gload_lds16(Ab1 + k0, &As[bn][off1]);
            gload_lds16(Ab2 + k0, &As[bn][off2]);
            gload_lds16(Bb1 + k0, &Bs[bn][off1]);
            gload_lds16(Bb2 + k0, &Bs[bn][off2]);
            asm volatile("s_waitcnt vmcnt(4)\n\ts_barrier" ::: "memory");
        } else {
            asm volatile("s_waitcnt vmcnt(0)\n\ts_barrier" ::: "memory");
        }
        bf16x8 af[4], bfr[4];
#pragma unroll
        for (int mi = 0; mi < 4; ++mi)
            af[mi] = *(const bf16x8*)&As[bc][(wm + mi * 16 + l16) * 32 + pc];
#pragma unroll
        for (int ni = 0; ni < 4; ++ni)
            bfr[ni] = *(const bf16x8*)&Bs[bc][(wn + ni * 16 + l16) * 32 + pc];
#pragma unroll
        for (int mi = 0; mi < 4; ++mi)
#pragma unroll
            for (int ni = 0; ni < 4; ++ni)
                acc[mi][ni] = __builtin_amdgcn_mfma_f32_16x16x32_bf16(
                    af[mi], bfr[ni], acc[mi][ni], 0, 0, 0);
        bc = bn;
    }

    // epilogue: fp32 store + block max + one atomic
    float vmax = -__builtin_inff();
#pragma unroll
    for (int mi = 0; mi < 4; ++mi)
#pragma unroll
        for (int ni = 0; ni < 4; ++ni) {
            int col = nBase + wn + ni * 16 + l16;
#pragma unroll
            for (int r = 0; r < 4; ++r) {
                int row = mBase + wm + mi * 16 + quad * 4 + r;
                float v = acc[mi][ni][r];
                C[(size_t)row * N + col] = v;
                vmax = fmaxf(vmax, v);
            }
        }
#pragma unroll
    for (int off = 32; off > 0; off >>= 1)
        vmax = fmaxf(vmax, __shfl_xor(vmax, off));
    if (lane == 0) redbuf[wave] = vmax;
    __syncthreads();
    if (tid == 0) {
        float m = redbuf[0];
#pragma unroll
        for (int w = 1; w < 4; ++w) m = fmaxf(m, redbuf[w]);
        if (m >= 0.0f) atomicMax((int*)maxp, __float_as_int(m));
        else           atomicMin((unsigned int*)maxp, __float_as_uint(m));
    }
}

// ---------------------------------------------------------------------------
__global__ void scale_kernel(float* __restrict__ out, const float* __restrict__ maxp) {
    int i = blockIdx.x * blockDim.x + threadIdx.x;
    float inv = 1.0f / (*maxp);
    float4* o4 = (float4*)out;
    float4 v = o4[i];
    v.x *= inv; v.y *= inv; v.z *= inv; v.w *= inv;
    o4[i] = v;
}

// ---------------------------------------------------------------------------
extern "C" void kernel_launch(void* const* d_in, const int* in_sizes, int n_in,
                              void* d_out, int out_size, void* d_ws, size_t ws_size,
                              hipStream_t stream) {
    const float* x  = (const float*)d_in[0];  // (4096, 2048)
    const float* W  = (const float*)d_in[1];  // (2074, 2048)
    const float* cb = (const float*)d_in[2];  // (2074, 2048)

    char* ws = (char*)d_ws;
    unsigned short* xb   = (unsigned short*)ws;                                   // [4096][2048] bf16
    unsigned short* WT   = (unsigned short*)(ws + (size_t)BATCH * LAT * 2);       // [2048][2112] bf16
    unsigned short* cosT = (unsigned short*)((char*)WT + (size_t)LAT * KPAD * 2);
    unsigned short* C1   = (unsigned short*)((char*)cosT + (size_t)LAT * KPAD * 2); // [2048][2048] bf16
    float*          maxp = (float*)((char*)C1 + (size_t)LAT * LAT * 2);
    float*          out  = (float*)d_out;

    // 1. fused prep: cast x -> bf16 (+init max), transpose+cast W and cos_basis
    prep_kernel<<<4096 + 2 * 1056, 256, 0, stream>>>(x, W, cb, xb, WT, cosT, maxp);

    // 2. C1[l2][l1] = sum_f cosT[l2,f] * WT[l1,f]   (128x64 tiles, 512 blocks)
    gemm1_kernel<LAT, KPAD>
        <<<dim3(LAT / 64, LAT / 128), 256, 0, stream>>>(cosT, WT, C1);

    // 3. out[b][l2] = sum_l1 xb[b][l1] * C1[l2][l1]  (128x128, 256 thr,
    //    64x64 wave tiles, fused max)
    gemm2_kernel<LAT, LAT>
        <<<dim3(LAT / 128, BATCH / 128), 256, 0, stream>>>(xb, C1, out, maxp);

    // 4. out /= max
    scale_kernel<<<(out_size / 4) / 256, 256, 0, stream>>>(out, maxp);
}